// Round 2
// baseline (234.333 us; speedup 1.0000x reference)
//
#include <hip/hip_runtime.h>
#include <hip/hip_bf16.h>

#define NEG_SLOPE 0.2f
#define CAP1   512   // edges into target (realistic ~21)
#define CAPS   64    // unique source nodes incl target (realistic ~21)
#define CAP2   6144  // edges into any node of S (realistic ~470)
#define MAXDEG 256   // per-node in-degree cap inside layer-1 block

// Dual-dtype loader: flag==1 -> buffer is float32, else bf16.
__device__ __forceinline__ float ldf(const void* p, int i, int f32) {
    if (f32) return ((const float*)p)[i];
    return __bfloat162float(((const __hip_bfloat16*)p)[i]);
}

// ---------------------------------------------------------------------------
// K0 (1 block): detect input dtype from x's bit patterns + zero counters.
// bf16 N(0,1): exponent field in ~[0x6E,0x82], never 0 or >=0xC0.
// fp32 reinterpreted as u16: low halves are random mantissa bits -> ~25% weird.
__global__ void k_init(const void* __restrict__ x, int* W, float* easum) {
    __shared__ int weird;
    if (threadIdx.x == 0) weird = 0;
    __syncthreads();
    const unsigned short* u = (const unsigned short*)x;
    int cnt = 0;
    for (int i = threadIdx.x; i < 2048; i += 256) {
        int e = (u[i] >> 7) & 0xFF;
        if (e == 0 || e >= 0xC0) cnt++;
    }
    atomicAdd(&weird, cnt);
    __syncthreads();
    if (threadIdx.x == 0) {
        W[0] = 0; W[1] = 0; W[2] = 0;      // cnt1, cntS, cnt2
        W[3] = (weird >= 64) ? 1 : 0;      // f32 flag
        easum[0] = 0.f;
    }
}

// ---------------------------------------------------------------------------
// K1: one pass over edges: sum(edge_attr) + collect edges with dst == target
__global__ void k_scan1(const int* __restrict__ src, const int* __restrict__ dst,
                        const void* __restrict__ ea, const int* __restrict__ tgt,
                        int E, int* W, float* easum, int* l1src, float* l1ea) {
    __shared__ float sred[4];
    int f32 = W[3];
    int i = blockIdx.x * blockDim.x + threadIdx.x;
    int t = tgt[0];
    float v = 0.f;
    if (i < E) {
        v = ldf(ea, i, f32);
        if (dst[i] == t) {
            int p = atomicAdd(&W[0], 1);
            if (p < CAP1) { l1src[p] = src[i]; l1ea[p] = v; }
        }
    }
    for (int o = 32; o > 0; o >>= 1) v += __shfl_down(v, o);
    if ((threadIdx.x & 63) == 0) sred[threadIdx.x >> 6] = v;
    __syncthreads();
    if (threadIdx.x == 0)
        atomicAdd(easum, sred[0] + sred[1] + sred[2] + sred[3]);
}

// ---------------------------------------------------------------------------
// K2 (1 thread): append target self-loop, build unique source set S, seed
//                list2 with self-loops for every node in S.
__global__ void k_build(const int* __restrict__ tgt, int E,
                        int* W, const float* easum,
                        int* l1src, float* l1ea, int* slist,
                        int* l2src, int* l2dst, float* l2ea) {
    if (threadIdx.x != 0) return;
    int t = tgt[0];
    float mean = easum[0] / (float)E;
    int c1 = W[0]; if (c1 > CAP1 - 1) c1 = CAP1 - 1;
    l1src[c1] = t; l1ea[c1] = mean; c1++;   // self-loop for target
    W[0] = c1;
    int ns = 0;
    for (int e = 0; e < c1; e++) {
        int s = l1src[e];
        bool found = false;
        for (int j = 0; j < ns; j++) if (slist[j] == s) { found = true; break; }
        if (!found && ns < CAPS) { slist[ns] = s; ns++; }
    }
    W[1] = ns;
    for (int i = 0; i < ns; i++) {          // self-loops for every s in S
        l2src[i] = slist[i]; l2dst[i] = slist[i]; l2ea[i] = mean;
    }
    W[2] = ns;
}

// ---------------------------------------------------------------------------
// K3: second pass over edges: collect edges whose dst is in S (linear-scan
//     membership over <=64-entry slist held in LDS)
__global__ void k_scan2(const int* __restrict__ src, const int* __restrict__ dst,
                        const void* __restrict__ ea, int E,
                        int* W, const int* __restrict__ slist,
                        int* l2src, int* l2dst, float* l2ea) {
    __shared__ int ss[CAPS];
    __shared__ int sn;
    int f32 = W[3];
    if (threadIdx.x == 0) sn = W[1] > CAPS ? CAPS : W[1];
    if (threadIdx.x < CAPS) ss[threadIdx.x] = slist[threadIdx.x];
    __syncthreads();
    int ns = sn;
    int i = blockIdx.x * blockDim.x + threadIdx.x;
    if (i >= E) return;
    int d = dst[i];
    for (int j = 0; j < ns; j++) {
        if (ss[j] == d) {
            int p = atomicAdd(&W[2], 1);
            if (p < CAP2) { l2src[p] = src[i]; l2dst[p] = d; l2ea[p] = ldf(ea, i, f32); }
            break;
        }
    }
}

// ---------------------------------------------------------------------------
// K4: per node s in S (one block each): full GATv2 layer-1 at s (softmax over
//     its incoming edges), relu, then xl2[s] = h1[s]@Wl2+bl2 (xr2 for target).
__global__ void __launch_bounds__(128)
k_layer1(const void* __restrict__ x,
         const void* __restrict__ Wl1, const void* __restrict__ bl1,
         const void* __restrict__ Wr1, const void* __restrict__ br1,
         const void* __restrict__ We1, const void* __restrict__ att1,
         const void* __restrict__ b1,
         const void* __restrict__ Wl2, const void* __restrict__ bl2,
         const void* __restrict__ Wr2, const void* __restrict__ br2,
         const int* __restrict__ tgt,
         const int* __restrict__ W, const int* __restrict__ slist,
         const int* __restrict__ l2src, const int* __restrict__ l2dst,
         const float* __restrict__ l2ea,
         float* xl2, float* xr2) {
    __shared__ float sWl[128], sBl[128], sWe[128], sAtt[128], sB1[128], sBase[128];
    __shared__ float sXs[MAXDEG], sEa[MAXDEG], sL0[MAXDEG], sL1[MAXDEG];
    __shared__ float sH[128];
    __shared__ int sDeg;

    int f32 = W[3];
    int ns = W[1]; if (ns > CAPS) ns = CAPS;
    int b = blockIdx.x;
    if (b >= ns) return;
    int s = slist[b];
    int tid = threadIdx.x;

    float xt = ldf(x, s, f32);
    sWl[tid] = ldf(Wl1, tid, f32);  sBl[tid] = ldf(bl1, tid, f32);
    sWe[tid] = ldf(We1, tid, f32);  sAtt[tid] = ldf(att1, tid, f32);
    sB1[tid] = ldf(b1, tid, f32);
    sBase[tid] = xt * ldf(Wr1, tid, f32) + ldf(br1, tid, f32);
    if (tid == 0) sDeg = 0;
    __syncthreads();

    int c2 = W[2]; if (c2 > CAP2) c2 = CAP2;
    for (int e = tid; e < c2; e += 128) {
        if (l2dst[e] == s) {
            int p = atomicAdd(&sDeg, 1);
            if (p < MAXDEG) { sXs[p] = ldf(x, l2src[e], f32); sEa[p] = l2ea[e]; }
        }
    }
    __syncthreads();
    int deg = sDeg; if (deg > MAXDEG) deg = MAXDEG;

    // per-edge attention logits: a^T leakyrelu(xl_j + xr_i + e_ij), 2 heads
    for (int i = tid; i < deg; i += 128) {
        float xs = sXs[i], eav = sEa[i];
        float l0 = 0.f, l1v = 0.f;
        for (int c = 0; c < 128; c++) {
            float v = xs * sWl[c] + sBl[c] + sBase[c] + eav * sWe[c];
            v = v > 0.f ? v : NEG_SLOPE * v;
            float w = v * sAtt[c];
            if (c < 64) l0 += w; else l1v += w;
        }
        sL0[i] = l0; sL1[i] = l1v;
    }
    __syncthreads();

    if (tid == 0) {   // softmax over <=~50 edges: serial is fine
        float m0 = -1e30f, m1 = -1e30f;
        for (int i = 0; i < deg; i++) { m0 = fmaxf(m0, sL0[i]); m1 = fmaxf(m1, sL1[i]); }
        float s0 = 0.f, s1 = 0.f;
        for (int i = 0; i < deg; i++) {
            sL0[i] = __expf(sL0[i] - m0); s0 += sL0[i];
            sL1[i] = __expf(sL1[i] - m1); s1 += sL1[i];
        }
        float r0 = 1.f / s0, r1 = 1.f / s1;
        for (int i = 0; i < deg; i++) { sL0[i] *= r0; sL1[i] *= r1; }
    }
    __syncthreads();

    {   // aggregate msg = xl[src]*alpha, add bias, relu
        int c = tid;
        bool hi = c >= 64;
        float acc = 0.f;
        for (int i = 0; i < deg; i++) {
            float a = hi ? sL1[i] : sL0[i];
            acc += a * (sXs[i] * sWl[c] + sBl[c]);
        }
        acc += sB1[c];
        acc = fmaxf(acc, 0.f);           // relu after conv1
        sH[c] = acc;
    }
    __syncthreads();

    {   // xl2[b] = sH @ Wl2 + bl2 ; xr2 only for the target node
        int c = tid;
        float acc = ldf(bl2, c, f32);
        for (int k = 0; k < 128; k++) acc += sH[k] * ldf(Wl2, k * 128 + c, f32);
        xl2[b * 128 + c] = acc;
        if (s == tgt[0]) {
            float a2 = ldf(br2, c, f32);
            for (int k = 0; k < 128; k++) a2 += sH[k] * ldf(Wr2, k * 128 + c, f32);
            xr2[c] = a2;
        }
    }
}

// ---------------------------------------------------------------------------
// K5 (1 block, 128 thr): layer-2 attention at target + aggregation + FC
__global__ void __launch_bounds__(128)
k_final(const void* __restrict__ We2, const void* __restrict__ att2,
        const void* __restrict__ b2v,
        const void* __restrict__ Wfc, const void* __restrict__ bfc,
        const int* __restrict__ W, const int* __restrict__ l1src,
        const float* __restrict__ l1ea, const int* __restrict__ slist,
        const float* __restrict__ xl2, const float* __restrict__ xr2,
        void* __restrict__ out) {
    __shared__ float sl0[CAP1], sl1[CAP1];
    __shared__ int sslot[CAP1];
    __shared__ float semb[128];

    int tid = threadIdx.x;
    int f32 = W[3];
    int c1 = W[0]; if (c1 > CAP1) c1 = CAP1;
    int ns = W[1]; if (ns > CAPS) ns = CAPS;

    // resolve src -> slot in parallel (<=64-entry scan each)
    for (int e = tid; e < c1; e += 128) {
        int s = l1src[e];
        int slot = 0;
        for (int j = 0; j < ns; j++) if (slist[j] == s) { slot = j; break; }
        sslot[e] = slot;
    }
    __syncthreads();

    float xr = xr2[tid];
    float we = ldf(We2, tid, f32);
    float at = ldf(att2, tid, f32);

    for (int e = 0; e < c1; e++) {
        int slot = sslot[e];
        float v = xl2[slot * 128 + tid] + xr + l1ea[e] * we;
        v = v > 0.f ? v : NEG_SLOPE * v;
        float w = v * at;
        for (int o = 32; o > 0; o >>= 1) w += __shfl_down(w, o);
        if (tid == 0)  sl0[e] = w;
        if (tid == 64) sl1[e] = w;
    }
    __syncthreads();

    if (tid == 0) {
        float m0 = -1e30f, m1 = -1e30f;
        for (int e = 0; e < c1; e++) { m0 = fmaxf(m0, sl0[e]); m1 = fmaxf(m1, sl1[e]); }
        float s0 = 0.f, s1 = 0.f;
        for (int e = 0; e < c1; e++) {
            sl0[e] = __expf(sl0[e] - m0); s0 += sl0[e];
            sl1[e] = __expf(sl1[e] - m1); s1 += sl1[e];
        }
        float r0 = 1.f / s0, r1 = 1.f / s1;
        for (int e = 0; e < c1; e++) { sl0[e] *= r0; sl1[e] *= r1; }
    }
    __syncthreads();

    {   // out2[c] = sum_e alpha[e, h(c)] * xl2[slot_e][c] + b2[c]   (no relu)
        bool hi = tid >= 64;
        float acc = ldf(b2v, tid, f32);
        for (int e = 0; e < c1; e++) {
            float a = hi ? sl1[e] : sl0[e];
            acc += a * xl2[sslot[e] * 128 + tid];
        }
        semb[tid] = acc;
    }
    __syncthreads();

    {   // FC: out[j] = emb @ Wfc[:, j] + bfc[j]
        float o = ldf(bfc, tid, f32);
        for (int c = 0; c < 128; c++) o += semb[c] * ldf(Wfc, c * 128 + tid, f32);
        if (f32) ((float*)out)[tid] = o;
        else     ((__hip_bfloat16*)out)[tid] = __float2bfloat16(o);
    }
}

// ---------------------------------------------------------------------------
extern "C" void kernel_launch(void* const* d_in, const int* in_sizes, int n_in,
                              void* d_out, int out_size, void* d_ws, size_t ws_size,
                              hipStream_t stream) {
    const void* x    = d_in[0];
    const int*  eidx = (const int*)d_in[1];
    const void* eattr= d_in[2];
    const int*  tgt  = (const int*)d_in[3];
    const void* Wl1 = d_in[4],  *bl1 = d_in[5],  *Wr1 = d_in[6],  *br1 = d_in[7];
    const void* We1 = d_in[8],  *att1= d_in[9],  *b1  = d_in[10];
    const void* Wl2 = d_in[11], *bl2 = d_in[12], *Wr2 = d_in[13], *br2 = d_in[14];
    const void* We2 = d_in[15], *att2= d_in[16], *b2v = d_in[17];
    const void* Wfc = d_in[18], *bfc = d_in[19];

    int E = in_sizes[1] / 2;
    const int* src = eidx;
    const int* dst = eidx + E;

    // workspace layout (4-byte words), total ~111 KB
    int* W      = (int*)d_ws;            // [0]=cnt1 [1]=cntS [2]=cnt2 [3]=f32flag
    float* easum= (float*)(W + 4);
    int* l1src  = W + 8;
    float* l1ea = (float*)(W + 8 + CAP1);
    int* slist  = W + 8 + 2 * CAP1;
    int* l2src  = W + 8 + 2 * CAP1 + CAPS;
    int* l2dst  = l2src + CAP2;
    float* l2ea = (float*)(l2dst + CAP2);
    float* xl2  = (float*)(l2ea + CAP2);
    float* xr2  = xl2 + CAPS * 128;

    k_init <<<1, 256, 0, stream>>>(x, W, easum);
    k_scan1<<<(E + 255) / 256, 256, 0, stream>>>(src, dst, eattr, tgt, E,
                                                 W, easum, l1src, l1ea);
    k_build<<<1, 64, 0, stream>>>(tgt, E, W, easum, l1src, l1ea, slist,
                                  l2src, l2dst, l2ea);
    k_scan2<<<(E + 255) / 256, 256, 0, stream>>>(src, dst, eattr, E, W, slist,
                                                 l2src, l2dst, l2ea);
    k_layer1<<<CAPS, 128, 0, stream>>>(x, Wl1, bl1, Wr1, br1, We1, att1, b1,
                                       Wl2, bl2, Wr2, br2, tgt,
                                       W, slist, l2src, l2dst, l2ea,
                                       xl2, xr2);
    k_final<<<1, 128, 0, stream>>>(We2, att2, b2v, Wfc, bfc,
                                   W, l1src, l1ea, slist, xl2, xr2, d_out);
}

// Round 3
// 190.998 us; speedup vs baseline: 1.2269x; 1.2269x over previous
//
#include <hip/hip_runtime.h>
#include <hip/hip_bf16.h>

#define NEG_SLOPE 0.2f
#define CAP1   512   // edges into target (realistic ~21)
#define CAPS   64    // unique source nodes incl target (realistic ~21)
#define CAP2   6144  // edges into any node of S (realistic ~470)
#define MAXDEG 256   // per-node in-degree cap inside layer-1 block
#define NB     512   // scan grid blocks (fixed, grid-stride)

// Dual-dtype loader: flag==1 -> buffer is float32, else bf16.
__device__ __forceinline__ float ldf(const void* p, int i, int f32) {
    if (f32) return ((const float*)p)[i];
    return __bfloat162float(((const __hip_bfloat16*)p)[i]);
}
// bf16 bits (as ushort) -> float
__device__ __forceinline__ float us2f(unsigned short s) {
    union { unsigned int u; float f; } c;
    c.u = ((unsigned int)s) << 16;
    return c.f;
}

// ---------------------------------------------------------------------------
// K0 (1 block): detect input dtype from x's bit patterns + zero counters.
// bf16 N(0,1): exponent field in ~[0x6E,0x82], never 0 or >=0xC0.
// fp32 reinterpreted as u16: low halves are random mantissa bits -> ~25% weird.
__global__ void k_init(const void* __restrict__ x, int* W) {
    __shared__ int weird;
    if (threadIdx.x == 0) weird = 0;
    __syncthreads();
    const unsigned short* u = (const unsigned short*)x;
    int cnt = 0;
    for (int i = threadIdx.x; i < 2048; i += 256) {
        int e = (u[i] >> 7) & 0xFF;
        if (e == 0 || e >= 0xC0) cnt++;
    }
    atomicAdd(&weird, cnt);
    __syncthreads();
    if (threadIdx.x == 0) {
        W[0] = 0; W[1] = 0; W[2] = 0;      // cnt1, cntS, cnt2
        W[3] = (weird >= 64) ? 1 : 0;      // f32 flag
    }
}

// ---------------------------------------------------------------------------
// K1: grid-stride vectorized pass over edges: per-block partial of
//     sum(edge_attr) (NO same-address atomics) + collect edges dst == target.
__global__ void __launch_bounds__(256)
k_scan1(const int* __restrict__ src, const int* __restrict__ dst,
        const void* __restrict__ ea, const int* __restrict__ tgt,
        int E, int* W, float* partials, int* l1src, float* l1ea) {
    __shared__ float sred[4];
    int f32 = W[3];
    int t = tgt[0];
    int E4 = E >> 2;
    int gid = blockIdx.x * blockDim.x + threadIdx.x;
    int stride = gridDim.x * blockDim.x;
    float sum = 0.f;
    for (int j = gid; j < E4; j += stride) {
        int4 d4 = ((const int4*)dst)[j];
        float v0, v1, v2, v3;
        if (f32) {
            float4 e4 = ((const float4*)ea)[j];
            v0 = e4.x; v1 = e4.y; v2 = e4.z; v3 = e4.w;
        } else {
            ushort4 u4 = ((const ushort4*)ea)[j];
            v0 = us2f(u4.x); v1 = us2f(u4.y); v2 = us2f(u4.z); v3 = us2f(u4.w);
        }
        sum += (v0 + v1) + (v2 + v3);
        int base = 4 * j;
        if (d4.x == t) { int p = atomicAdd(&W[0], 1); if (p < CAP1) { l1src[p] = src[base+0]; l1ea[p] = v0; } }
        if (d4.y == t) { int p = atomicAdd(&W[0], 1); if (p < CAP1) { l1src[p] = src[base+1]; l1ea[p] = v1; } }
        if (d4.z == t) { int p = atomicAdd(&W[0], 1); if (p < CAP1) { l1src[p] = src[base+2]; l1ea[p] = v2; } }
        if (d4.w == t) { int p = atomicAdd(&W[0], 1); if (p < CAP1) { l1src[p] = src[base+3]; l1ea[p] = v3; } }
    }
    int rem = E & 3;
    if (gid < rem) {
        int i = E4 * 4 + gid;
        float v = ldf(ea, i, f32);
        sum += v;
        if (dst[i] == t) { int p = atomicAdd(&W[0], 1); if (p < CAP1) { l1src[p] = src[i]; l1ea[p] = v; } }
    }
    for (int o = 32; o > 0; o >>= 1) sum += __shfl_down(sum, o);
    if ((threadIdx.x & 63) == 0) sred[threadIdx.x >> 6] = sum;
    __syncthreads();
    if (threadIdx.x == 0)
        partials[blockIdx.x] = sred[0] + sred[1] + sred[2] + sred[3];
}

// ---------------------------------------------------------------------------
// K2 (1 block, 256 thr): reduce partials -> mean; append target self-loop,
//     build unique source set S, seed list2 with self-loops for S.
__global__ void __launch_bounds__(256)
k_build(const int* __restrict__ tgt, int E,
        int* W, const float* __restrict__ partials,
        int* l1src, float* l1ea, int* slist,
        int* l2src, int* l2dst, float* l2ea) {
    __shared__ float sred[4];
    float s = 0.f;
    for (int i = threadIdx.x; i < NB; i += 256) s += partials[i];
    for (int o = 32; o > 0; o >>= 1) s += __shfl_down(s, o);
    if ((threadIdx.x & 63) == 0) sred[threadIdx.x >> 6] = s;
    __syncthreads();
    if (threadIdx.x != 0) return;
    float mean = (sred[0] + sred[1] + sred[2] + sred[3]) / (float)E;
    int t = tgt[0];
    int c1 = W[0]; if (c1 > CAP1 - 1) c1 = CAP1 - 1;
    l1src[c1] = t; l1ea[c1] = mean; c1++;   // self-loop for target
    W[0] = c1;
    int ns = 0;
    for (int e = 0; e < c1; e++) {
        int sv = l1src[e];
        bool found = false;
        for (int j = 0; j < ns; j++) if (slist[j] == sv) { found = true; break; }
        if (!found && ns < CAPS) { slist[ns] = sv; ns++; }
    }
    W[1] = ns;
    for (int i = 0; i < ns; i++) {          // self-loops for every s in S
        l2src[i] = slist[i]; l2dst[i] = slist[i]; l2ea[i] = mean;
    }
    W[2] = ns;
}

// ---------------------------------------------------------------------------
// K3: grid-stride vectorized pass: collect edges whose dst is in S.
//     Streams only dst (int4); touches edge_attr only on match (~500 loads).
__global__ void __launch_bounds__(256)
k_scan2(const int* __restrict__ src, const int* __restrict__ dst,
        const void* __restrict__ ea, int E,
        int* W, const int* __restrict__ slist,
        int* l2src, int* l2dst, float* l2ea) {
    __shared__ int ss[CAPS];
    __shared__ int sn;
    if (threadIdx.x == 0) sn = W[1] > CAPS ? CAPS : W[1];
    if (threadIdx.x < CAPS) ss[threadIdx.x] = slist[threadIdx.x];
    __syncthreads();
    int ns = sn;
    int f32 = W[3];
    int E4 = E >> 2;
    int gid = blockIdx.x * blockDim.x + threadIdx.x;
    int stride = gridDim.x * blockDim.x;

    #define CHECK(dv, idx)                                                     \
        do {                                                                   \
            for (int j_ = 0; j_ < ns; j_++) {                                  \
                if (ss[j_] == (dv)) {                                          \
                    int p_ = atomicAdd(&W[2], 1);                              \
                    if (p_ < CAP2) {                                           \
                        l2src[p_] = src[idx]; l2dst[p_] = (dv);                \
                        l2ea[p_] = ldf(ea, idx, f32);                          \
                    }                                                          \
                    break;                                                     \
                }                                                              \
            }                                                                  \
        } while (0)

    for (int j = gid; j < E4; j += stride) {
        int4 d4 = ((const int4*)dst)[j];
        int base = 4 * j;
        CHECK(d4.x, base + 0);
        CHECK(d4.y, base + 1);
        CHECK(d4.z, base + 2);
        CHECK(d4.w, base + 3);
    }
    int rem = E & 3;
    if (gid < rem) {
        int i = E4 * 4 + gid;
        CHECK(dst[i], i);
    }
    #undef CHECK
}

// ---------------------------------------------------------------------------
// K4: per node s in S (one block each): full GATv2 layer-1 at s (softmax over
//     its incoming edges), relu, then xl2[s] = h1[s]@Wl2+bl2 (xr2 for target).
__global__ void __launch_bounds__(128)
k_layer1(const void* __restrict__ x,
         const void* __restrict__ Wl1, const void* __restrict__ bl1,
         const void* __restrict__ Wr1, const void* __restrict__ br1,
         const void* __restrict__ We1, const void* __restrict__ att1,
         const void* __restrict__ b1,
         const void* __restrict__ Wl2, const void* __restrict__ bl2,
         const void* __restrict__ Wr2, const void* __restrict__ br2,
         const int* __restrict__ tgt,
         const int* __restrict__ W, const int* __restrict__ slist,
         const int* __restrict__ l2src, const int* __restrict__ l2dst,
         const float* __restrict__ l2ea,
         float* xl2, float* xr2) {
    __shared__ float sWl[128], sBl[128], sWe[128], sAtt[128], sB1[128], sBase[128];
    __shared__ float sXs[MAXDEG], sEa[MAXDEG], sL0[MAXDEG], sL1[MAXDEG];
    __shared__ float sH[128];
    __shared__ int sDeg;

    int f32 = W[3];
    int ns = W[1]; if (ns > CAPS) ns = CAPS;
    int b = blockIdx.x;
    if (b >= ns) return;
    int s = slist[b];
    int tid = threadIdx.x;

    float xt = ldf(x, s, f32);
    sWl[tid] = ldf(Wl1, tid, f32);  sBl[tid] = ldf(bl1, tid, f32);
    sWe[tid] = ldf(We1, tid, f32);  sAtt[tid] = ldf(att1, tid, f32);
    sB1[tid] = ldf(b1, tid, f32);
    sBase[tid] = xt * ldf(Wr1, tid, f32) + ldf(br1, tid, f32);
    if (tid == 0) sDeg = 0;
    __syncthreads();

    int c2 = W[2]; if (c2 > CAP2) c2 = CAP2;
    for (int e = tid; e < c2; e += 128) {
        if (l2dst[e] == s) {
            int p = atomicAdd(&sDeg, 1);
            if (p < MAXDEG) { sXs[p] = ldf(x, l2src[e], f32); sEa[p] = l2ea[e]; }
        }
    }
    __syncthreads();
    int deg = sDeg; if (deg > MAXDEG) deg = MAXDEG;

    // per-edge attention logits: a^T leakyrelu(xl_j + xr_i + e_ij), 2 heads
    for (int i = tid; i < deg; i += 128) {
        float xs = sXs[i], eav = sEa[i];
        float l0 = 0.f, l1v = 0.f;
        for (int c = 0; c < 128; c++) {
            float v = xs * sWl[c] + sBl[c] + sBase[c] + eav * sWe[c];
            v = v > 0.f ? v : NEG_SLOPE * v;
            float w = v * sAtt[c];
            if (c < 64) l0 += w; else l1v += w;
        }
        sL0[i] = l0; sL1[i] = l1v;
    }
    __syncthreads();

    if (tid == 0) {   // softmax over <=~50 edges: serial is fine
        float m0 = -1e30f, m1 = -1e30f;
        for (int i = 0; i < deg; i++) { m0 = fmaxf(m0, sL0[i]); m1 = fmaxf(m1, sL1[i]); }
        float s0 = 0.f, s1 = 0.f;
        for (int i = 0; i < deg; i++) {
            sL0[i] = __expf(sL0[i] - m0); s0 += sL0[i];
            sL1[i] = __expf(sL1[i] - m1); s1 += sL1[i];
        }
        float r0 = 1.f / s0, r1 = 1.f / s1;
        for (int i = 0; i < deg; i++) { sL0[i] *= r0; sL1[i] *= r1; }
    }
    __syncthreads();

    {   // aggregate msg = xl[src]*alpha, add bias, relu
        int c = tid;
        bool hi = c >= 64;
        float acc = 0.f;
        for (int i = 0; i < deg; i++) {
            float a = hi ? sL1[i] : sL0[i];
            acc += a * (sXs[i] * sWl[c] + sBl[c]);
        }
        acc += sB1[c];
        acc = fmaxf(acc, 0.f);           // relu after conv1
        sH[c] = acc;
    }
    __syncthreads();

    {   // xl2[b] = sH @ Wl2 + bl2 ; xr2 only for the target node
        int c = tid;
        float acc = ldf(bl2, c, f32);
        for (int k = 0; k < 128; k++) acc += sH[k] * ldf(Wl2, k * 128 + c, f32);
        xl2[b * 128 + c] = acc;
        if (s == tgt[0]) {
            float a2 = ldf(br2, c, f32);
            for (int k = 0; k < 128; k++) a2 += sH[k] * ldf(Wr2, k * 128 + c, f32);
            xr2[c] = a2;
        }
    }
}

// ---------------------------------------------------------------------------
// K5 (1 block, 128 thr): layer-2 attention at target + aggregation + FC
__global__ void __launch_bounds__(128)
k_final(const void* __restrict__ We2, const void* __restrict__ att2,
        const void* __restrict__ b2v,
        const void* __restrict__ Wfc, const void* __restrict__ bfc,
        const int* __restrict__ W, const int* __restrict__ l1src,
        const float* __restrict__ l1ea, const int* __restrict__ slist,
        const float* __restrict__ xl2, const float* __restrict__ xr2,
        void* __restrict__ out) {
    __shared__ float sl0[CAP1], sl1[CAP1];
    __shared__ int sslot[CAP1];
    __shared__ float semb[128];

    int tid = threadIdx.x;
    int f32 = W[3];
    int c1 = W[0]; if (c1 > CAP1) c1 = CAP1;
    int ns = W[1]; if (ns > CAPS) ns = CAPS;

    // resolve src -> slot in parallel (<=64-entry scan each)
    for (int e = tid; e < c1; e += 128) {
        int s = l1src[e];
        int slot = 0;
        for (int j = 0; j < ns; j++) if (slist[j] == s) { slot = j; break; }
        sslot[e] = slot;
    }
    __syncthreads();

    float xr = xr2[tid];
    float we = ldf(We2, tid, f32);
    float at = ldf(att2, tid, f32);

    for (int e = 0; e < c1; e++) {
        int slot = sslot[e];
        float v = xl2[slot * 128 + tid] + xr + l1ea[e] * we;
        v = v > 0.f ? v : NEG_SLOPE * v;
        float w = v * at;
        for (int o = 32; o > 0; o >>= 1) w += __shfl_down(w, o);
        if (tid == 0)  sl0[e] = w;
        if (tid == 64) sl1[e] = w;
    }
    __syncthreads();

    if (tid == 0) {
        float m0 = -1e30f, m1 = -1e30f;
        for (int e = 0; e < c1; e++) { m0 = fmaxf(m0, sl0[e]); m1 = fmaxf(m1, sl1[e]); }
        float s0 = 0.f, s1 = 0.f;
        for (int e = 0; e < c1; e++) {
            sl0[e] = __expf(sl0[e] - m0); s0 += sl0[e];
            sl1[e] = __expf(sl1[e] - m1); s1 += sl1[e];
        }
        float r0 = 1.f / s0, r1 = 1.f / s1;
        for (int e = 0; e < c1; e++) { sl0[e] *= r0; sl1[e] *= r1; }
    }
    __syncthreads();

    {   // out2[c] = sum_e alpha[e, h(c)] * xl2[slot_e][c] + b2[c]   (no relu)
        bool hi = tid >= 64;
        float acc = ldf(b2v, tid, f32);
        for (int e = 0; e < c1; e++) {
            float a = hi ? sl1[e] : sl0[e];
            acc += a * xl2[sslot[e] * 128 + tid];
        }
        semb[tid] = acc;
    }
    __syncthreads();

    {   // FC: out[j] = emb @ Wfc[:, j] + bfc[j]
        float o = ldf(bfc, tid, f32);
        for (int c = 0; c < 128; c++) o += semb[c] * ldf(Wfc, c * 128 + tid, f32);
        if (f32) ((float*)out)[tid] = o;
        else     ((__hip_bfloat16*)out)[tid] = __float2bfloat16(o);
    }
}

// ---------------------------------------------------------------------------
extern "C" void kernel_launch(void* const* d_in, const int* in_sizes, int n_in,
                              void* d_out, int out_size, void* d_ws, size_t ws_size,
                              hipStream_t stream) {
    const void* x    = d_in[0];
    const int*  eidx = (const int*)d_in[1];
    const void* eattr= d_in[2];
    const int*  tgt  = (const int*)d_in[3];
    const void* Wl1 = d_in[4],  *bl1 = d_in[5],  *Wr1 = d_in[6],  *br1 = d_in[7];
    const void* We1 = d_in[8],  *att1= d_in[9],  *b1  = d_in[10];
    const void* Wl2 = d_in[11], *bl2 = d_in[12], *Wr2 = d_in[13], *br2 = d_in[14];
    const void* We2 = d_in[15], *att2= d_in[16], *b2v = d_in[17];
    const void* Wfc = d_in[18], *bfc = d_in[19];

    int E = in_sizes[1] / 2;
    const int* src = eidx;
    const int* dst = eidx + E;

    // workspace layout (4-byte words), total ~113 KB
    int* W       = (int*)d_ws;           // [0]=cnt1 [1]=cntS [2]=cnt2 [3]=f32flag
    float* parts = (float*)(W + 8);      // NB partials
    int* l1src   = W + 8 + NB;
    float* l1ea  = (float*)(l1src + CAP1);
    int* slist   = (int*)(l1ea + CAP1);
    int* l2src   = slist + CAPS;
    int* l2dst   = l2src + CAP2;
    float* l2ea  = (float*)(l2dst + CAP2);
    float* xl2   = (float*)(l2ea + CAP2);
    float* xr2   = xl2 + CAPS * 128;

    k_init <<<1, 256, 0, stream>>>(x, W);
    k_scan1<<<NB, 256, 0, stream>>>(src, dst, eattr, tgt, E,
                                    W, parts, l1src, l1ea);
    k_build<<<1, 256, 0, stream>>>(tgt, E, W, parts, l1src, l1ea, slist,
                                   l2src, l2dst, l2ea);
    k_scan2<<<NB, 256, 0, stream>>>(src, dst, eattr, E, W, slist,
                                    l2src, l2dst, l2ea);
    k_layer1<<<CAPS, 128, 0, stream>>>(x, Wl1, bl1, Wr1, br1, We1, att1, b1,
                                       Wl2, bl2, Wr2, br2, tgt,
                                       W, slist, l2src, l2dst, l2ea,
                                       xl2, xr2);
    k_final<<<1, 128, 0, stream>>>(We2, att2, b2v, Wfc, bfc,
                                   W, l1src, l1ea, slist, xl2, xr2, d_out);
}

// Round 4
// 165.061 us; speedup vs baseline: 1.4197x; 1.1571x over previous
//
#include <hip/hip_runtime.h>
#include <hip/hip_bf16.h>

#define NEG_SLOPE 0.2f
#define CAP1   512   // edges into target (realistic ~21)
#define CAPS   64    // unique source nodes incl target (realistic ~21)
#define CAP2   6144  // edges into any node of S (realistic ~470)
#define MAXDEG 256   // per-node in-degree cap inside layer-1 block
#define NB     512   // scan grid blocks (fixed, grid-stride)

// bf16 bits (as ushort) -> float
__device__ __forceinline__ float us2f(unsigned short s) {
    union { unsigned int u; float f; } c;
    c.u = ((unsigned int)s) << 16;
    return c.f;
}
// Compile-time dtype loader: branchless inner loops.
template<bool F32>
__device__ __forceinline__ float tld(const void* p, int i) {
    if (F32) return ((const float*)p)[i];
    return us2f(((const unsigned short*)p)[i]);
}

// ---------------------------------------------------------------------------
// K0 (1 block): detect input dtype from x's bit patterns + zero counters.
// bf16 N(0,1): exponent field in ~[0x6E,0x82], never 0 or >=0xC0.
// fp32 reinterpreted as u16: low halves are random mantissa bits -> ~25% weird.
__global__ void k_init(const void* __restrict__ x, int* W) {
    __shared__ int weird;
    if (threadIdx.x == 0) weird = 0;
    __syncthreads();
    const unsigned short* u = (const unsigned short*)x;
    int cnt = 0;
    for (int i = threadIdx.x; i < 2048; i += 256) {
        int e = (u[i] >> 7) & 0xFF;
        if (e == 0 || e >= 0xC0) cnt++;
    }
    atomicAdd(&weird, cnt);
    __syncthreads();
    if (threadIdx.x == 0) {
        W[0] = 0; W[1] = 0; W[2] = 0;      // cnt1, cntS, cnt2
        W[3] = (weird >= 64) ? 1 : 0;      // f32 flag
    }
}

// ---------------------------------------------------------------------------
// K1: grid-stride vectorized pass over edges: per-block partial of
//     sum(edge_attr) + collect edges dst == target.
template<bool F32>
__device__ __forceinline__ void scan1_body(
        const int* __restrict__ src, const int* __restrict__ dst,
        const void* __restrict__ ea, int t, int E,
        int* W, float* partials, int* l1src, float* l1ea) {
    __shared__ float sred[4];
    int E4 = E >> 2;
    int gid = blockIdx.x * blockDim.x + threadIdx.x;
    int stride = gridDim.x * blockDim.x;
    float sum = 0.f;
    for (int j = gid; j < E4; j += stride) {
        int4 d4 = ((const int4*)dst)[j];
        float v0, v1, v2, v3;
        if (F32) {
            float4 e4 = ((const float4*)ea)[j];
            v0 = e4.x; v1 = e4.y; v2 = e4.z; v3 = e4.w;
        } else {
            ushort4 u4 = ((const ushort4*)ea)[j];
            v0 = us2f(u4.x); v1 = us2f(u4.y); v2 = us2f(u4.z); v3 = us2f(u4.w);
        }
        sum += (v0 + v1) + (v2 + v3);
        int base = 4 * j;
        if (d4.x == t) { int p = atomicAdd(&W[0], 1); if (p < CAP1) { l1src[p] = src[base+0]; l1ea[p] = v0; } }
        if (d4.y == t) { int p = atomicAdd(&W[0], 1); if (p < CAP1) { l1src[p] = src[base+1]; l1ea[p] = v1; } }
        if (d4.z == t) { int p = atomicAdd(&W[0], 1); if (p < CAP1) { l1src[p] = src[base+2]; l1ea[p] = v2; } }
        if (d4.w == t) { int p = atomicAdd(&W[0], 1); if (p < CAP1) { l1src[p] = src[base+3]; l1ea[p] = v3; } }
    }
    int rem = E & 3;
    if (gid < rem) {
        int i = E4 * 4 + gid;
        float v = tld<F32>(ea, i);
        sum += v;
        if (dst[i] == t) { int p = atomicAdd(&W[0], 1); if (p < CAP1) { l1src[p] = src[i]; l1ea[p] = v; } }
    }
    for (int o = 32; o > 0; o >>= 1) sum += __shfl_down(sum, o);
    if ((threadIdx.x & 63) == 0) sred[threadIdx.x >> 6] = sum;
    __syncthreads();
    if (threadIdx.x == 0)
        partials[blockIdx.x] = sred[0] + sred[1] + sred[2] + sred[3];
}

__global__ void __launch_bounds__(256)
k_scan1(const int* __restrict__ src, const int* __restrict__ dst,
        const void* __restrict__ ea, const int* __restrict__ tgt,
        int E, int* W, float* partials, int* l1src, float* l1ea) {
    int t = tgt[0];
    if (W[3]) scan1_body<true >(src, dst, ea, t, E, W, partials, l1src, l1ea);
    else      scan1_body<false>(src, dst, ea, t, E, W, partials, l1src, l1ea);
}

// ---------------------------------------------------------------------------
// K2 (1 block, 256 thr): reduce partials -> mean; append target self-loop,
//     build unique source set S, seed list2 with self-loops for S.
__global__ void __launch_bounds__(256)
k_build(const int* __restrict__ tgt, int E,
        int* W, const float* __restrict__ partials,
        int* l1src, float* l1ea, int* slist,
        int* l2src, int* l2dst, float* l2ea) {
    __shared__ float sred[4];
    float s = 0.f;
    for (int i = threadIdx.x; i < NB; i += 256) s += partials[i];
    for (int o = 32; o > 0; o >>= 1) s += __shfl_down(s, o);
    if ((threadIdx.x & 63) == 0) sred[threadIdx.x >> 6] = s;
    __syncthreads();
    if (threadIdx.x != 0) return;
    float mean = (sred[0] + sred[1] + sred[2] + sred[3]) / (float)E;
    int t = tgt[0];
    int c1 = W[0]; if (c1 > CAP1 - 1) c1 = CAP1 - 1;
    l1src[c1] = t; l1ea[c1] = mean; c1++;   // self-loop for target
    W[0] = c1;
    int ns = 0;
    for (int e = 0; e < c1; e++) {
        int sv = l1src[e];
        bool found = false;
        for (int j = 0; j < ns; j++) if (slist[j] == sv) { found = true; break; }
        if (!found && ns < CAPS) { slist[ns] = sv; ns++; }
    }
    W[1] = ns;
    for (int i = 0; i < ns; i++) {          // self-loops for every s in S
        l2src[i] = slist[i]; l2dst[i] = slist[i]; l2ea[i] = mean;
    }
    W[2] = ns;
}

// ---------------------------------------------------------------------------
// K3: grid-stride vectorized pass: collect edges whose dst is in S.
//     Streams only dst (int4); touches edge_attr only on match.
template<bool F32>
__device__ __forceinline__ void scan2_body(
        const int* __restrict__ src, const int* __restrict__ dst,
        const void* __restrict__ ea, int E, int ns, const int* ss,
        int* W, int* l2src, int* l2dst, float* l2ea) {
    int E4 = E >> 2;
    int gid = blockIdx.x * blockDim.x + threadIdx.x;
    int stride = gridDim.x * blockDim.x;

    #define CHECK(dv, idx)                                                     \
        do {                                                                   \
            for (int j_ = 0; j_ < ns; j_++) {                                  \
                if (ss[j_] == (dv)) {                                          \
                    int p_ = atomicAdd(&W[2], 1);                              \
                    if (p_ < CAP2) {                                           \
                        l2src[p_] = src[idx]; l2dst[p_] = (dv);                \
                        l2ea[p_] = tld<F32>(ea, idx);                          \
                    }                                                          \
                    break;                                                     \
                }                                                              \
            }                                                                  \
        } while (0)

    for (int j = gid; j < E4; j += stride) {
        int4 d4 = ((const int4*)dst)[j];
        int base = 4 * j;
        CHECK(d4.x, base + 0);
        CHECK(d4.y, base + 1);
        CHECK(d4.z, base + 2);
        CHECK(d4.w, base + 3);
    }
    int rem = E & 3;
    if (gid < rem) {
        int i = E4 * 4 + gid;
        CHECK(dst[i], i);
    }
    #undef CHECK
}

__global__ void __launch_bounds__(256)
k_scan2(const int* __restrict__ src, const int* __restrict__ dst,
        const void* __restrict__ ea, int E,
        int* W, const int* __restrict__ slist,
        int* l2src, int* l2dst, float* l2ea) {
    __shared__ int ss[CAPS];
    __shared__ int sn;
    if (threadIdx.x == 0) sn = W[1] > CAPS ? CAPS : W[1];
    if (threadIdx.x < CAPS) ss[threadIdx.x] = slist[threadIdx.x];
    __syncthreads();
    int ns = sn;
    if (W[3]) scan2_body<true >(src, dst, ea, E, ns, ss, W, l2src, l2dst, l2ea);
    else      scan2_body<false>(src, dst, ea, E, ns, ss, W, l2src, l2dst, l2ea);
}

// ---------------------------------------------------------------------------
// K4: per node s in S (one block each): full GATv2 layer-1 at s, relu, then
//     xl2[s] = h1[s]@Wl2+bl2 (xr2 for target).
template<bool F32>
__device__ __forceinline__ void layer1_body(
        const void* __restrict__ x,
        const void* __restrict__ Wl1, const void* __restrict__ bl1,
        const void* __restrict__ Wr1, const void* __restrict__ br1,
        const void* __restrict__ We1, const void* __restrict__ att1,
        const void* __restrict__ b1,
        const void* __restrict__ Wl2, const void* __restrict__ bl2,
        const void* __restrict__ Wr2, const void* __restrict__ br2,
        int tgt0, const int* __restrict__ W, const int* __restrict__ slist,
        const int* __restrict__ l2src, const int* __restrict__ l2dst,
        const float* __restrict__ l2ea,
        float* xl2, float* xr2) {
    __shared__ float sWl[128], sBl[128], sWe[128], sAtt[128], sB1[128], sBase[128];
    __shared__ float sXs[MAXDEG], sEa[MAXDEG], sL0[MAXDEG], sL1[MAXDEG];
    __shared__ float sH[128];
    __shared__ int sDeg;

    int s = slist[blockIdx.x];
    int tid = threadIdx.x;

    float xt = tld<F32>(x, s);
    sWl[tid] = tld<F32>(Wl1, tid);  sBl[tid] = tld<F32>(bl1, tid);
    sWe[tid] = tld<F32>(We1, tid);  sAtt[tid] = tld<F32>(att1, tid);
    sB1[tid] = tld<F32>(b1, tid);
    sBase[tid] = xt * tld<F32>(Wr1, tid) + tld<F32>(br1, tid);
    if (tid == 0) sDeg = 0;
    __syncthreads();

    int c2 = W[2]; if (c2 > CAP2) c2 = CAP2;
    for (int e = tid; e < c2; e += 128) {
        if (l2dst[e] == s) {
            int p = atomicAdd(&sDeg, 1);
            if (p < MAXDEG) { sXs[p] = tld<F32>(x, l2src[e]); sEa[p] = l2ea[e]; }
        }
    }
    __syncthreads();
    int deg = sDeg; if (deg > MAXDEG) deg = MAXDEG;

    // per-edge attention logits: a^T leakyrelu(xl_j + xr_i + e_ij), 2 heads
    for (int i = tid; i < deg; i += 128) {
        float xs = sXs[i], eav = sEa[i];
        float l0 = 0.f, l1v = 0.f;
        #pragma unroll 8
        for (int c = 0; c < 128; c++) {
            float v = xs * sWl[c] + sBl[c] + sBase[c] + eav * sWe[c];
            v = v > 0.f ? v : NEG_SLOPE * v;
            float w = v * sAtt[c];
            if (c < 64) l0 += w; else l1v += w;
        }
        sL0[i] = l0; sL1[i] = l1v;
    }
    __syncthreads();

    if (tid == 0) {   // softmax over <=~50 edges: serial is fine
        float m0 = -1e30f, m1 = -1e30f;
        for (int i = 0; i < deg; i++) { m0 = fmaxf(m0, sL0[i]); m1 = fmaxf(m1, sL1[i]); }
        float s0 = 0.f, s1 = 0.f;
        for (int i = 0; i < deg; i++) {
            sL0[i] = __expf(sL0[i] - m0); s0 += sL0[i];
            sL1[i] = __expf(sL1[i] - m1); s1 += sL1[i];
        }
        float r0 = 1.f / s0, r1 = 1.f / s1;
        for (int i = 0; i < deg; i++) { sL0[i] *= r0; sL1[i] *= r1; }
    }
    __syncthreads();

    {   // aggregate msg = xl[src]*alpha, add bias, relu
        int c = tid;
        bool hi = c >= 64;
        float acc = 0.f;
        for (int i = 0; i < deg; i++) {
            float a = hi ? sL1[i] : sL0[i];
            acc += a * (sXs[i] * sWl[c] + sBl[c]);
        }
        acc += sB1[c];
        acc = fmaxf(acc, 0.f);           // relu after conv1
        sH[c] = acc;
    }
    __syncthreads();

    {   // xl2[b] = sH @ Wl2 + bl2 ; xr2 only for the target node
        int c = tid;
        float acc = tld<F32>(bl2, c);
        #pragma unroll 16
        for (int k = 0; k < 128; k++) acc += sH[k] * tld<F32>(Wl2, k * 128 + c);
        xl2[blockIdx.x * 128 + c] = acc;
        if (s == tgt0) {
            float a2 = tld<F32>(br2, c);
            #pragma unroll 16
            for (int k = 0; k < 128; k++) a2 += sH[k] * tld<F32>(Wr2, k * 128 + c);
            xr2[c] = a2;
        }
    }
}

__global__ void __launch_bounds__(128)
k_layer1(const void* __restrict__ x,
         const void* __restrict__ Wl1, const void* __restrict__ bl1,
         const void* __restrict__ Wr1, const void* __restrict__ br1,
         const void* __restrict__ We1, const void* __restrict__ att1,
         const void* __restrict__ b1,
         const void* __restrict__ Wl2, const void* __restrict__ bl2,
         const void* __restrict__ Wr2, const void* __restrict__ br2,
         const int* __restrict__ tgt,
         const int* __restrict__ W, const int* __restrict__ slist,
         const int* __restrict__ l2src, const int* __restrict__ l2dst,
         const float* __restrict__ l2ea,
         float* xl2, float* xr2) {
    int ns = W[1]; if (ns > CAPS) ns = CAPS;
    if ((int)blockIdx.x >= ns) return;
    if (W[3]) layer1_body<true >(x, Wl1, bl1, Wr1, br1, We1, att1, b1,
                                 Wl2, bl2, Wr2, br2, tgt[0], W, slist,
                                 l2src, l2dst, l2ea, xl2, xr2);
    else      layer1_body<false>(x, Wl1, bl1, Wr1, br1, We1, att1, b1,
                                 Wl2, bl2, Wr2, br2, tgt[0], W, slist,
                                 l2src, l2dst, l2ea, xl2, xr2);
}

// ---------------------------------------------------------------------------
// K5 (1 block, 128 thr): layer-2 attention at target + aggregation + FC
template<bool F32>
__device__ __forceinline__ void final_body(
        const void* __restrict__ We2, const void* __restrict__ att2,
        const void* __restrict__ b2v,
        const void* __restrict__ Wfc, const void* __restrict__ bfc,
        const int* __restrict__ W, const int* __restrict__ l1src,
        const float* __restrict__ l1ea, const int* __restrict__ slist,
        const float* __restrict__ xl2, const float* __restrict__ xr2,
        void* __restrict__ out) {
    __shared__ float sl0[CAP1], sl1[CAP1];
    __shared__ int sslot[CAP1];
    __shared__ float semb[128];

    int tid = threadIdx.x;
    int c1 = W[0]; if (c1 > CAP1) c1 = CAP1;
    int ns = W[1]; if (ns > CAPS) ns = CAPS;

    // resolve src -> slot in parallel (<=64-entry scan each)
    for (int e = tid; e < c1; e += 128) {
        int s = l1src[e];
        int slot = 0;
        for (int j = 0; j < ns; j++) if (slist[j] == s) { slot = j; break; }
        sslot[e] = slot;
    }
    __syncthreads();

    float xr = xr2[tid];
    float we = tld<F32>(We2, tid);
    float at = tld<F32>(att2, tid);

    for (int e = 0; e < c1; e++) {
        int slot = sslot[e];
        float v = xl2[slot * 128 + tid] + xr + l1ea[e] * we;
        v = v > 0.f ? v : NEG_SLOPE * v;
        float w = v * at;
        for (int o = 32; o > 0; o >>= 1) w += __shfl_down(w, o);
        if (tid == 0)  sl0[e] = w;
        if (tid == 64) sl1[e] = w;
    }
    __syncthreads();

    if (tid == 0) {
        float m0 = -1e30f, m1 = -1e30f;
        for (int e = 0; e < c1; e++) { m0 = fmaxf(m0, sl0[e]); m1 = fmaxf(m1, sl1[e]); }
        float s0 = 0.f, s1 = 0.f;
        for (int e = 0; e < c1; e++) {
            sl0[e] = __expf(sl0[e] - m0); s0 += sl0[e];
            sl1[e] = __expf(sl1[e] - m1); s1 += sl1[e];
        }
        float r0 = 1.f / s0, r1 = 1.f / s1;
        for (int e = 0; e < c1; e++) { sl0[e] *= r0; sl1[e] *= r1; }
    }
    __syncthreads();

    {   // out2[c] = sum_e alpha[e, h(c)] * xl2[slot_e][c] + b2[c]   (no relu)
        bool hi = tid >= 64;
        float acc = tld<F32>(b2v, tid);
        for (int e = 0; e < c1; e++) {
            float a = hi ? sl1[e] : sl0[e];
            acc += a * xl2[sslot[e] * 128 + tid];
        }
        semb[tid] = acc;
    }
    __syncthreads();

    {   // FC: out[j] = emb @ Wfc[:, j] + bfc[j]
        float o = tld<F32>(bfc, tid);
        #pragma unroll 16
        for (int c = 0; c < 128; c++) o += semb[c] * tld<F32>(Wfc, c * 128 + tid);
        if (F32) ((float*)out)[tid] = o;
        else     ((__hip_bfloat16*)out)[tid] = __float2bfloat16(o);
    }
}

__global__ void __launch_bounds__(128)
k_final(const void* __restrict__ We2, const void* __restrict__ att2,
        const void* __restrict__ b2v,
        const void* __restrict__ Wfc, const void* __restrict__ bfc,
        const int* __restrict__ W, const int* __restrict__ l1src,
        const float* __restrict__ l1ea, const int* __restrict__ slist,
        const float* __restrict__ xl2, const float* __restrict__ xr2,
        void* __restrict__ out) {
    if (W[3]) final_body<true >(We2, att2, b2v, Wfc, bfc, W, l1src, l1ea,
                                slist, xl2, xr2, out);
    else      final_body<false>(We2, att2, b2v, Wfc, bfc, W, l1src, l1ea,
                                slist, xl2, xr2, out);
}

// ---------------------------------------------------------------------------
extern "C" void kernel_launch(void* const* d_in, const int* in_sizes, int n_in,
                              void* d_out, int out_size, void* d_ws, size_t ws_size,
                              hipStream_t stream) {
    const void* x    = d_in[0];
    const int*  eidx = (const int*)d_in[1];
    const void* eattr= d_in[2];
    const int*  tgt  = (const int*)d_in[3];
    const void* Wl1 = d_in[4],  *bl1 = d_in[5],  *Wr1 = d_in[6],  *br1 = d_in[7];
    const void* We1 = d_in[8],  *att1= d_in[9],  *b1  = d_in[10];
    const void* Wl2 = d_in[11], *bl2 = d_in[12], *Wr2 = d_in[13], *br2 = d_in[14];
    const void* We2 = d_in[15], *att2= d_in[16], *b2v = d_in[17];
    const void* Wfc = d_in[18], *bfc = d_in[19];

    int E = in_sizes[1] / 2;
    const int* src = eidx;
    const int* dst = eidx + E;

    // workspace layout (4-byte words), total ~113 KB
    int* W       = (int*)d_ws;           // [0]=cnt1 [1]=cntS [2]=cnt2 [3]=f32flag
    float* parts = (float*)(W + 8);      // NB partials
    int* l1src   = W + 8 + NB;
    float* l1ea  = (float*)(l1src + CAP1);
    int* slist   = (int*)(l1ea + CAP1);
    int* l2src   = slist + CAPS;
    int* l2dst   = l2src + CAP2;
    float* l2ea  = (float*)(l2dst + CAP2);
    float* xl2   = (float*)(l2ea + CAP2);
    float* xr2   = xl2 + CAPS * 128;

    k_init <<<1, 256, 0, stream>>>(x, W);
    k_scan1<<<NB, 256, 0, stream>>>(src, dst, eattr, tgt, E,
                                    W, parts, l1src, l1ea);
    k_build<<<1, 256, 0, stream>>>(tgt, E, W, parts, l1src, l1ea, slist,
                                   l2src, l2dst, l2ea);
    k_scan2<<<NB, 256, 0, stream>>>(src, dst, eattr, E, W, slist,
                                    l2src, l2dst, l2ea);
    k_layer1<<<CAPS, 128, 0, stream>>>(x, Wl1, bl1, Wr1, br1, We1, att1, b1,
                                       Wl2, bl2, Wr2, br2, tgt,
                                       W, slist, l2src, l2dst, l2ea,
                                       xl2, xr2);
    k_final<<<1, 128, 0, stream>>>(We2, att2, b2v, Wfc, bfc,
                                   W, l1src, l1ea, slist, xl2, xr2, d_out);
}